// Round 1
// baseline (1875.725 us; speedup 1.0000x reference)
//
#include <hip/hip_runtime.h>

#define B_ 32
#define P_ 256
#define N_ 1024
#define E_ 512
#define H_ 16
#define D_ 32

static_assert(E_ == H_ * D_, "");

// Intermediates in static device memory (graph-capture safe, no ws_size assumption).
__device__ float g_q[B_ * P_ * E_];    // (q_first + x@Wq^T) * rsqrt(D), layout [B,P,H*D]
__device__ float g_att[B_ * P_ * E_];  // attention out_concat, layout [B,P,E]
__device__ float g_mh[B_ * P_ * E_];   // mh_atten_out, layout [B,P,E]

// ---------------------------------------------------------------------------
// K1 (MODE=1): g_q = (encoded @ Wq^T + q_first) * rsqrt(32)
// K3 (MODE=0): g_mh = g_att @ Wc^T
// Tile: 256 rows x 32 cols, K=512 in chunks of 16. 256 threads, 1 row/thread,
// 32 cols in registers. A staged in LDS (stride 260: conflict-free row reads);
// B read as uniform-address float4 broadcasts (scalarizable).
// ---------------------------------------------------------------------------
template <int MODE>
__global__ __launch_bounds__(256) void gemm_abt(const float* __restrict__ A,
                                                const float* __restrict__ Bt,
                                                const float* __restrict__ qf)
{
    __shared__ float As[16][260];
    __shared__ float Ls[256][33];
    const int t = threadIdx.x;
    const int col0 = blockIdx.x * 32;
    const int row0 = blockIdx.y * 256;
    const float* Ain = (MODE == 1) ? A : g_att;
    float* C = (MODE == 1) ? g_q : g_mh;

    float acc[32];
#pragma unroll
    for (int c = 0; c < 32; ++c) acc[c] = 0.f;

    const int r_ld = t >> 2;
    const int ks = (t & 3) * 4;
    for (int kc = 0; kc < 512; kc += 16) {
        __syncthreads();
#pragma unroll
        for (int ps = 0; ps < 4; ++ps) {
            int row = r_ld + ps * 64;
            float4 a4 = *(const float4*)(Ain + (size_t)(row0 + row) * 512 + kc + ks);
            As[ks + 0][row] = a4.x; As[ks + 1][row] = a4.y;
            As[ks + 2][row] = a4.z; As[ks + 3][row] = a4.w;
        }
        __syncthreads();
#pragma unroll
        for (int kq = 0; kq < 4; ++kq) {
            float a0 = As[kq * 4 + 0][t];
            float a1 = As[kq * 4 + 1][t];
            float a2 = As[kq * 4 + 2][t];
            float a3 = As[kq * 4 + 3][t];
#pragma unroll
            for (int c = 0; c < 32; ++c) {
                float4 b4 = *(const float4*)(Bt + (size_t)(col0 + c) * 512 + kc + kq * 4);
                acc[c] = fmaf(a3, b4.w, fmaf(a2, b4.z, fmaf(a1, b4.y, fmaf(a0, b4.x, acc[c]))));
            }
        }
    }

    const int cq = t & 7, rr = t >> 3;
    __syncthreads();
    if (MODE == 1) {
        const int b = blockIdx.y;  // 256-row tile == one batch
        const int h = blockIdx.x;  // 32-col tile == one head
        const float* src = qf + (size_t)(b * H_ + h) * P_ * D_;  // contiguous [256][32]
#pragma unroll
        for (int ps = 0; ps < 8; ++ps) {
            int i = ps * 1024 + t * 4;
            float4 v4 = *(const float4*)(src + i);
            int p = i >> 5, d = i & 31;
            Ls[p][d + 0] = v4.x; Ls[p][d + 1] = v4.y;
            Ls[p][d + 2] = v4.z; Ls[p][d + 3] = v4.w;
        }
        __syncthreads();
        const float s = 0.17677669529663687f;  // rsqrt(32): pre-scale q once
#pragma unroll
        for (int c = 0; c < 32; ++c) Ls[t][c] = (acc[c] + Ls[t][c]) * s;
    } else {
#pragma unroll
        for (int c = 0; c < 32; ++c) Ls[t][c] = acc[c];
    }
    __syncthreads();
#pragma unroll
    for (int ps = 0; ps < 8; ++ps) {
        int row = rr + ps * 32;
        float4 o4 = make_float4(Ls[row][cq * 4 + 0], Ls[row][cq * 4 + 1],
                                Ls[row][cq * 4 + 2], Ls[row][cq * 4 + 3]);
        *(float4*)(C + (size_t)(row0 + row) * 512 + col0 + cq * 4) = o4;
    }
}

__device__ __forceinline__ float dot4(float4 kv, const float* q)
{
    return fmaf(q[3], kv.w, fmaf(q[2], kv.z, fmaf(q[1], kv.y, q[0] * kv.x)));
}

// ---------------------------------------------------------------------------
// K2: masked MHA per (b,h). 256 threads = 256 queries, online softmax with
// FIXED max m0=12 (scores provably <~8; masked -> exp(-1e9)=0), so no rescale.
// k/v rows are uniform-address broadcasts; mask staged via LDS per 32-n chunk.
// ---------------------------------------------------------------------------
__global__ __launch_bounds__(256) void attn_kernel(const float* __restrict__ kg,
                                                   const float* __restrict__ vg,
                                                   const float* __restrict__ mask)
{
    __shared__ float Lm[256][33];
    const int t = threadIdx.x;
    const int b = blockIdx.x >> 4;
    const int h = blockIdx.x & 15;
    const float* kb = kg + (size_t)(b * H_ + h) * N_ * D_;
    const float* vb = vg + (size_t)(b * H_ + h) * N_ * D_;
    const int cq = t & 7, rr = t >> 3;

    // stage this (b,h)'s q slice [256 p][32 d] (coalesced), read own row
#pragma unroll
    for (int ps = 0; ps < 8; ++ps) {
        int row = rr + ps * 32;
        float4 qv = *(const float4*)(g_q + (size_t)(b * P_ + row) * E_ + h * D_ + cq * 4);
        Lm[row][cq * 4 + 0] = qv.x; Lm[row][cq * 4 + 1] = qv.y;
        Lm[row][cq * 4 + 2] = qv.z; Lm[row][cq * 4 + 3] = qv.w;
    }
    __syncthreads();
    float qr[32];
#pragma unroll
    for (int d = 0; d < 32; ++d) qr[d] = Lm[t][d];

    float o[32];
#pragma unroll
    for (int d = 0; d < 32; ++d) o[d] = 0.f;
    float l = 0.f;

    for (int nc = 0; nc < N_; nc += 32) {
        __syncthreads();  // previous chunk's Lm reads done
#pragma unroll
        for (int ps = 0; ps < 8; ++ps) {
            int row = rr + ps * 32;
            float4 mv = *(const float4*)(mask + (size_t)(b * P_ + row) * N_ + nc + cq * 4);
            Lm[row][cq * 4 + 0] = mv.x; Lm[row][cq * 4 + 1] = mv.y;
            Lm[row][cq * 4 + 2] = mv.z; Lm[row][cq * 4 + 3] = mv.w;
        }
        __syncthreads();
#pragma unroll 2
        for (int nn = 0; nn < 32; ++nn) {
            const float4* kr = (const float4*)(kb + (size_t)(nc + nn) * D_);
            float sd0 = dot4(kr[0], qr + 0)  + dot4(kr[1], qr + 4);
            float sd1 = dot4(kr[2], qr + 8)  + dot4(kr[3], qr + 12);
            float sd2 = dot4(kr[4], qr + 16) + dot4(kr[5], qr + 20);
            float sd3 = dot4(kr[6], qr + 24) + dot4(kr[7], qr + 28);
            float sc = ((sd0 + sd1) + (sd2 + sd3)) + Lm[t][nn];
            float p = __expf(sc - 12.0f);
            l += p;
            const float4* vr = (const float4*)(vb + (size_t)(nc + nn) * D_);
#pragma unroll
            for (int j = 0; j < 8; ++j) {
                float4 v4 = vr[j];
                o[j * 4 + 0] = fmaf(p, v4.x, o[j * 4 + 0]);
                o[j * 4 + 1] = fmaf(p, v4.y, o[j * 4 + 1]);
                o[j * 4 + 2] = fmaf(p, v4.z, o[j * 4 + 2]);
                o[j * 4 + 3] = fmaf(p, v4.w, o[j * 4 + 3]);
            }
        }
    }

    float invl = 1.0f / l;
    __syncthreads();
#pragma unroll
    for (int d = 0; d < 32; ++d) Lm[t][d] = o[d] * invl;
    __syncthreads();
#pragma unroll
    for (int ps = 0; ps < 8; ++ps) {
        int row = rr + ps * 32;
        float4 o4 = make_float4(Lm[row][cq * 4 + 0], Lm[row][cq * 4 + 1],
                                Lm[row][cq * 4 + 2], Lm[row][cq * 4 + 3]);
        *(float4*)(g_att + (size_t)(b * P_ + row) * E_ + h * D_ + cq * 4) = o4;
    }
}

// ---------------------------------------------------------------------------
// K4: per-batch pointer GEMM: logits = 10*tanh((g_mh[b] @ shk[b]) / sqrt(E)) + mask.
// Tile: 256 rows (all p) x 64 cols, 1 row/thread, 64 cols in registers.
// shk rows broadcast (uniform float4 over n). Epilogue restaged in 2 halves.
// ---------------------------------------------------------------------------
__global__ __launch_bounds__(256) void gemm_ptr(const float* __restrict__ shk,
                                                const float* __restrict__ mask,
                                                float* __restrict__ out)
{
    __shared__ float As[16][260];
    __shared__ float Ls[256][33];
    const int t = threadIdx.x;
    const int b = blockIdx.y;
    const int col0 = blockIdx.x * 64;
    const float* A = g_mh + (size_t)b * P_ * E_;
    const float* Bm = shk + (size_t)b * E_ * N_;

    float acc[64];
#pragma unroll
    for (int c = 0; c < 64; ++c) acc[c] = 0.f;

    const int r_ld = t >> 2, ks = (t & 3) * 4;
    for (int kc = 0; kc < 512; kc += 16) {
        __syncthreads();
#pragma unroll
        for (int ps = 0; ps < 4; ++ps) {
            int row = r_ld + ps * 64;
            float4 a4 = *(const float4*)(A + (size_t)row * 512 + kc + ks);
            As[ks + 0][row] = a4.x; As[ks + 1][row] = a4.y;
            As[ks + 2][row] = a4.z; As[ks + 3][row] = a4.w;
        }
        __syncthreads();
#pragma unroll
        for (int kk = 0; kk < 16; ++kk) {
            float a = As[kk][t];
#pragma unroll
            for (int c4 = 0; c4 < 16; ++c4) {
                float4 b4 = *(const float4*)(Bm + (size_t)(kc + kk) * N_ + col0 + c4 * 4);
                acc[c4 * 4 + 0] = fmaf(a, b4.x, acc[c4 * 4 + 0]);
                acc[c4 * 4 + 1] = fmaf(a, b4.y, acc[c4 * 4 + 1]);
                acc[c4 * 4 + 2] = fmaf(a, b4.z, acc[c4 * 4 + 2]);
                acc[c4 * 4 + 3] = fmaf(a, b4.w, acc[c4 * 4 + 3]);
            }
        }
    }

    const float inv = 0.044194173824159216f;  // 1/sqrt(512)
    const int cq = t & 7, rr = t >> 3;
#pragma unroll
    for (int half = 0; half < 2; ++half) {
        __syncthreads();
#pragma unroll
        for (int ps = 0; ps < 8; ++ps) {
            int row = rr + ps * 32;
            float4 mv = *(const float4*)(mask + (size_t)(b * P_ + row) * N_ + col0 + half * 32 + cq * 4);
            Ls[row][cq * 4 + 0] = mv.x; Ls[row][cq * 4 + 1] = mv.y;
            Ls[row][cq * 4 + 2] = mv.z; Ls[row][cq * 4 + 3] = mv.w;
        }
        __syncthreads();
#pragma unroll
        for (int c = 0; c < 32; ++c)
            Ls[t][c] = 10.0f * tanhf(acc[half * 32 + c] * inv) + Ls[t][c];
        __syncthreads();
#pragma unroll
        for (int ps = 0; ps < 8; ++ps) {
            int row = rr + ps * 32;
            float4 o4 = make_float4(Ls[row][cq * 4 + 0], Ls[row][cq * 4 + 1],
                                    Ls[row][cq * 4 + 2], Ls[row][cq * 4 + 3]);
            *(float4*)(out + (size_t)(b * P_ + row) * N_ + col0 + half * 32 + cq * 4) = o4;
        }
    }
}

// ---------------------------------------------------------------------------
// K5: in-place row softmax over d_out rows of 1024 (block per row).
// ---------------------------------------------------------------------------
__global__ __launch_bounds__(256) void softmax_rows(float* __restrict__ io)
{
    const int t = threadIdx.x;
    float* r = io + (size_t)blockIdx.x * N_;
    float4 x = *(const float4*)(r + t * 4);
    float m = fmaxf(fmaxf(x.x, x.y), fmaxf(x.z, x.w));
#pragma unroll
    for (int off = 32; off > 0; off >>= 1) m = fmaxf(m, __shfl_xor(m, off));
    __shared__ float red[8];
    if ((t & 63) == 0) red[t >> 6] = m;
    __syncthreads();
    m = fmaxf(fmaxf(red[0], red[1]), fmaxf(red[2], red[3]));
    float e0 = __expf(x.x - m), e1 = __expf(x.y - m);
    float e2 = __expf(x.z - m), e3 = __expf(x.w - m);
    float s = (e0 + e1) + (e2 + e3);
#pragma unroll
    for (int off = 32; off > 0; off >>= 1) s += __shfl_xor(s, off);
    if ((t & 63) == 0) red[4 + (t >> 6)] = s;
    __syncthreads();
    s = (red[4] + red[5]) + (red[6] + red[7]);
    float inv = 1.0f / s;
    *(float4*)(r + t * 4) = make_float4(e0 * inv, e1 * inv, e2 * inv, e3 * inv);
}

extern "C" void kernel_launch(void* const* d_in, const int* in_sizes, int n_in,
                              void* d_out, int out_size, void* d_ws, size_t ws_size,
                              hipStream_t stream)
{
    (void)in_sizes; (void)n_in; (void)d_ws; (void)ws_size; (void)out_size;
    const float* x   = (const float*)d_in[0];  // [B,P,E]
    const float* msk = (const float*)d_in[1];  // [B,P,N]
    const float* qf  = (const float*)d_in[2];  // [B,H,P,D]
    const float* kk  = (const float*)d_in[3];  // [B,H,N,D]
    const float* vv  = (const float*)d_in[4];  // [B,H,N,D]
    const float* shk = (const float*)d_in[5];  // [B,E,N]
    const float* wq  = (const float*)d_in[6];  // [E,E]
    const float* wc  = (const float*)d_in[7];  // [E,E]
    float* out = (float*)d_out;                // [B,P,N]

    gemm_abt<1><<<dim3(16, 32), 256, 0, stream>>>(x, wq, qf);        // g_q
    attn_kernel<<<dim3(B_ * H_), 256, 0, stream>>>(kk, vv, msk);     // g_att
    gemm_abt<0><<<dim3(16, 32), 256, 0, stream>>>(nullptr, wc, nullptr);  // g_mh
    gemm_ptr<<<dim3(16, 32), 256, 0, stream>>>(shk, msk, out);       // clipped logits
    softmax_rows<<<dim3(B_ * P_), 256, 0, stream>>>(out);            // probs
}

// Round 2
// 1314.680 us; speedup vs baseline: 1.4268x; 1.4268x over previous
//
#include <hip/hip_runtime.h>

#define B_ 32
#define P_ 256
#define N_ 1024
#define E_ 512
#define H_ 16
#define D_ 32

static_assert(E_ == H_ * D_, "");

typedef __attribute__((ext_vector_type(8))) short bf16x8;
typedef __attribute__((ext_vector_type(4))) float f32x4;

// Intermediates in static device memory (graph-capture safe).
__device__ float g_q[B_ * P_ * E_];    // (q_first + x@Wq^T) * rsqrt(32), [B,P,H*D]
__device__ float g_att[B_ * P_ * E_];  // attention out_concat, [B,P,E]
__device__ float g_mh[B_ * P_ * E_];   // mh_atten_out, [B,P,E]

__device__ __forceinline__ short bf16_hi(float x) {
    return (short)(__float_as_uint(x) >> 16);  // truncate to bf16
}
__device__ __forceinline__ float bf16_hi_f(float x) {
    return __uint_as_float(__float_as_uint(x) & 0xffff0000u);
}
// split x ~= hi + lo (each exactly a bf16); residual ~2^-16 relative
__device__ __forceinline__ void split8(const float* xv, bf16x8& h, bf16x8& l) {
#pragma unroll
    for (int j = 0; j < 8; ++j) {
        float x = xv[j];
        h[j] = bf16_hi(x);
        float r = x - bf16_hi_f(x);
        l[j] = bf16_hi(r);
    }
}

// ---------------------------------------------------------------------------
// K1 (MODE=1): g_q = (encoded @ Wq^T + q_first) * rsqrt(32)
// K3 (MODE=0): g_mh = g_att @ Wc^T              (unchanged from round 1)
// ---------------------------------------------------------------------------
template <int MODE>
__global__ __launch_bounds__(256) void gemm_abt(const float* __restrict__ A,
                                                const float* __restrict__ Bt,
                                                const float* __restrict__ qf)
{
    __shared__ float As[16][260];
    __shared__ float Ls[256][33];
    const int t = threadIdx.x;
    const int col0 = blockIdx.x * 32;
    const int row0 = blockIdx.y * 256;
    const float* Ain = (MODE == 1) ? A : g_att;
    float* C = (MODE == 1) ? g_q : g_mh;

    float acc[32];
#pragma unroll
    for (int c = 0; c < 32; ++c) acc[c] = 0.f;

    const int r_ld = t >> 2;
    const int ks = (t & 3) * 4;
    for (int kc = 0; kc < 512; kc += 16) {
        __syncthreads();
#pragma unroll
        for (int ps = 0; ps < 4; ++ps) {
            int row = r_ld + ps * 64;
            float4 a4 = *(const float4*)(Ain + (size_t)(row0 + row) * 512 + kc + ks);
            As[ks + 0][row] = a4.x; As[ks + 1][row] = a4.y;
            As[ks + 2][row] = a4.z; As[ks + 3][row] = a4.w;
        }
        __syncthreads();
#pragma unroll
        for (int kq = 0; kq < 4; ++kq) {
            float a0 = As[kq * 4 + 0][t];
            float a1 = As[kq * 4 + 1][t];
            float a2 = As[kq * 4 + 2][t];
            float a3 = As[kq * 4 + 3][t];
#pragma unroll
            for (int c = 0; c < 32; ++c) {
                float4 b4 = *(const float4*)(Bt + (size_t)(col0 + c) * 512 + kc + kq * 4);
                acc[c] = fmaf(a3, b4.w, fmaf(a2, b4.z, fmaf(a1, b4.y, fmaf(a0, b4.x, acc[c]))));
            }
        }
    }

    const int cq = t & 7, rr = t >> 3;
    __syncthreads();
    if (MODE == 1) {
        const int b = blockIdx.y;
        const int h = blockIdx.x;
        const float* src = qf + (size_t)(b * H_ + h) * P_ * D_;
#pragma unroll
        for (int ps = 0; ps < 8; ++ps) {
            int i = ps * 1024 + t * 4;
            float4 v4 = *(const float4*)(src + i);
            int p = i >> 5, d = i & 31;
            Ls[p][d + 0] = v4.x; Ls[p][d + 1] = v4.y;
            Ls[p][d + 2] = v4.z; Ls[p][d + 3] = v4.w;
        }
        __syncthreads();
        const float s = 0.17677669529663687f;  // rsqrt(32)
#pragma unroll
        for (int c = 0; c < 32; ++c) Ls[t][c] = (acc[c] + Ls[t][c]) * s;
    } else {
#pragma unroll
        for (int c = 0; c < 32; ++c) Ls[t][c] = acc[c];
    }
    __syncthreads();
#pragma unroll
    for (int ps = 0; ps < 8; ++ps) {
        int row = rr + ps * 32;
        float4 o4 = make_float4(Ls[row][cq * 4 + 0], Ls[row][cq * 4 + 1],
                                Ls[row][cq * 4 + 2], Ls[row][cq * 4 + 3]);
        *(float4*)(C + (size_t)(row0 + row) * 512 + col0 + cq * 4) = o4;
    }
}

// ---------------------------------------------------------------------------
// K2: MFMA flash attention, split-bf16 (fp32-equivalent accuracy).
// Block = one (b,h), 4 independent waves (NO barriers). Wave owns 64 q-rows
// (4 p-tiles of 16). Loop over N in chunks of 32 (2 n-tiles):
//   S = qh*kh + ql*kh + qh*kl  (3 MFMAs/tile, 16x16x32, K = D = 32)
//   P = exp(S + mask - 12)     (fixed max: scores are sigma~1.4, never near 12;
//                               exp cannot overflow below s~100 anyway)
//   P split hi/lo, packed u32, bounced through per-wave LDS (stride 36 dwords:
//   write pattern 2-way banked, b128 read pattern 2-way banked -> both free)
//   O += Ph*Vh + Ph*Vl + Pl*Vh (3 MFMAs/tile), l-sum in regs.
// A-frag: row=lane&15, k=8*(lane>>4)+j. B-frag: col=lane&15, k=8*(lane>>4)+j.
// D: col=lane&15, row=4*(lane>>4)+reg (verified layout, learn_hip m89/m91).
// ---------------------------------------------------------------------------
__global__ __launch_bounds__(256, 2) void attn_mfma(const float* __restrict__ kg,
                                                    const float* __restrict__ vg,
                                                    const float* __restrict__ mask)
{
    __shared__ __align__(16) unsigned P_lds[4][64 * 36];  // 36864 B
    const int t = threadIdx.x;
    const int w = t >> 6;
    const int lane = t & 63;
    const int q16 = lane >> 4;  // lane quarter
    const int c = lane & 15;
    const int b = blockIdx.x >> 4;
    const int h = blockIdx.x & 15;
    const float* kb = kg + (size_t)(b * H_ + h) * N_ * D_;
    const float* vb = vg + (size_t)(b * H_ + h) * N_ * D_;
    const float* mb = mask + (size_t)b * P_ * N_ + (size_t)(w * 64) * N_;
    unsigned* Pw = P_lds[w];

    // Q fragments for 4 p-tiles, split hi/lo. Row p = pt*16+c, k = d = 8*q16+j.
    bf16x8 qh[4], ql[4];
#pragma unroll
    for (int pt = 0; pt < 4; ++pt) {
        const float* qrow = g_q + (size_t)(b * P_ + w * 64 + pt * 16 + c) * E_ + h * D_ + q16 * 8;
        float4 x0 = *(const float4*)qrow;
        float4 x1 = *(const float4*)(qrow + 4);
        float xv[8] = {x0.x, x0.y, x0.z, x0.w, x1.x, x1.y, x1.z, x1.w};
        split8(xv, qh[pt], ql[pt]);
    }

    f32x4 acc[4][2];
#pragma unroll
    for (int pt = 0; pt < 4; ++pt)
#pragma unroll
        for (int dt = 0; dt < 2; ++dt) acc[pt][dt] = (f32x4){0.f, 0.f, 0.f, 0.f};
    float lsum[4][4];
#pragma unroll
    for (int pt = 0; pt < 4; ++pt)
#pragma unroll
        for (int r = 0; r < 4; ++r) lsum[pt][r] = 0.f;

#pragma unroll 1
    for (int n0 = 0; n0 < N_; n0 += 32) {
        // K fragments: col n = n0+nt*16+c, k = d = 8*q16+j  (B = K^T)
        bf16x8 kh[2], kl[2];
#pragma unroll
        for (int nt = 0; nt < 2; ++nt) {
            const float* krow = kb + (size_t)(n0 + nt * 16 + c) * D_ + q16 * 8;
            float4 x0 = *(const float4*)krow;
            float4 x1 = *(const float4*)(krow + 4);
            float xv[8] = {x0.x, x0.y, x0.z, x0.w, x1.x, x1.y, x1.z, x1.w};
            split8(xv, kh[nt], kl[nt]);
        }
        // V fragments: col d = dt*16+c, k = n = n0+8*q16+j
        bf16x8 vh[2], vl[2];
#pragma unroll
        for (int dt = 0; dt < 2; ++dt) {
            const float* vcol = vb + (size_t)(n0 + q16 * 8) * D_ + dt * 16 + c;
            float xv[8];
#pragma unroll
            for (int j = 0; j < 8; ++j) xv[j] = vcol[(size_t)j * D_];
            split8(xv, vh[dt], vl[dt]);
        }

        // QK^T -> P -> LDS (packed hi|lo u32)
#pragma unroll
        for (int pt = 0; pt < 4; ++pt) {
#pragma unroll
            for (int nt = 0; nt < 2; ++nt) {
                f32x4 s = (f32x4){0.f, 0.f, 0.f, 0.f};
                s = __builtin_amdgcn_mfma_f32_16x16x32_bf16(qh[pt], kh[nt], s, 0, 0, 0);
                s = __builtin_amdgcn_mfma_f32_16x16x32_bf16(ql[pt], kh[nt], s, 0, 0, 0);
                s = __builtin_amdgcn_mfma_f32_16x16x32_bf16(qh[pt], kl[nt], s, 0, 0, 0);
#pragma unroll
                for (int r = 0; r < 4; ++r) {
                    int prow = pt * 16 + 4 * q16 + r;           // local p (0..63)
                    int ncol = n0 + nt * 16 + c;
                    float sc = s[r] + mb[(size_t)prow * N_ + ncol];
                    float pe = __expf(sc - 12.0f);
                    lsum[pt][r] += pe;
                    float peh = bf16_hi_f(pe);
                    unsigned pk = (__float_as_uint(pe) >> 16) |
                                  ((__float_as_uint(pe - peh) >> 16) << 16);
                    Pw[prow * 36 + nt * 16 + c] = pk;
                }
            }
        }

        // PV: A-frag of P from LDS (row p = pt*16+c, k = n = 8*q16+j)
#pragma unroll
        for (int pt = 0; pt < 4; ++pt) {
            const unsigned* prd = &Pw[(pt * 16 + c) * 36 + q16 * 8];
            uint4 r0 = *(const uint4*)prd;
            uint4 r1 = *(const uint4*)(prd + 4);
            unsigned u[8] = {r0.x, r0.y, r0.z, r0.w, r1.x, r1.y, r1.z, r1.w};
            bf16x8 ph, plo;
#pragma unroll
            for (int j = 0; j < 8; ++j) {
                ph[j]  = (short)(u[j] & 0xffffu);
                plo[j] = (short)(u[j] >> 16);
            }
#pragma unroll
            for (int dt = 0; dt < 2; ++dt) {
                acc[pt][dt] = __builtin_amdgcn_mfma_f32_16x16x32_bf16(ph,  vh[dt], acc[pt][dt], 0, 0, 0);
                acc[pt][dt] = __builtin_amdgcn_mfma_f32_16x16x32_bf16(ph,  vl[dt], acc[pt][dt], 0, 0, 0);
                acc[pt][dt] = __builtin_amdgcn_mfma_f32_16x16x32_bf16(plo, vh[dt], acc[pt][dt], 0, 0, 0);
            }
        }
    }

    // reduce l over the 16 lanes sharing q16 (they hold distinct n columns)
#pragma unroll
    for (int pt = 0; pt < 4; ++pt)
#pragma unroll
        for (int r = 0; r < 4; ++r) {
            float v = lsum[pt][r];
            v += __shfl_xor(v, 1);
            v += __shfl_xor(v, 2);
            v += __shfl_xor(v, 4);
            v += __shfl_xor(v, 8);
            lsum[pt][r] = 1.0f / v;
        }

    // write out: D row = 4*q16+r matches lsum's p mapping
#pragma unroll
    for (int pt = 0; pt < 4; ++pt)
#pragma unroll
        for (int dt = 0; dt < 2; ++dt)
#pragma unroll
            for (int r = 0; r < 4; ++r) {
                int p = w * 64 + pt * 16 + 4 * q16 + r;
                g_att[(size_t)(b * P_ + p) * E_ + h * D_ + dt * 16 + c] =
                    acc[pt][dt][r] * lsum[pt][r];
            }
}

// ---------------------------------------------------------------------------
// K4: per-batch pointer GEMM (unchanged)
// ---------------------------------------------------------------------------
__global__ __launch_bounds__(256) void gemm_ptr(const float* __restrict__ shk,
                                                const float* __restrict__ mask,
                                                float* __restrict__ out)
{
    __shared__ float As[16][260];
    __shared__ float Ls[256][33];
    const int t = threadIdx.x;
    const int b = blockIdx.y;
    const int col0 = blockIdx.x * 64;
    const float* A = g_mh + (size_t)b * P_ * E_;
    const float* Bm = shk + (size_t)b * E_ * N_;

    float acc[64];
#pragma unroll
    for (int c = 0; c < 64; ++c) acc[c] = 0.f;

    const int r_ld = t >> 2, ks = (t & 3) * 4;
    for (int kc = 0; kc < 512; kc += 16) {
        __syncthreads();
#pragma unroll
        for (int ps = 0; ps < 4; ++ps) {
            int row = r_ld + ps * 64;
            float4 a4 = *(const float4*)(A + (size_t)row * 512 + kc + ks);
            As[ks + 0][row] = a4.x; As[ks + 1][row] = a4.y;
            As[ks + 2][row] = a4.z; As[ks + 3][row] = a4.w;
        }
        __syncthreads();
#pragma unroll
        for (int kk = 0; kk < 16; ++kk) {
            float a = As[kk][t];
#pragma unroll
            for (int c4 = 0; c4 < 16; ++c4) {
                float4 b4 = *(const float4*)(Bm + (size_t)(kc + kk) * N_ + col0 + c4 * 4);
                acc[c4 * 4 + 0] = fmaf(a, b4.x, acc[c4 * 4 + 0]);
                acc[c4 * 4 + 1] = fmaf(a, b4.y, acc[c4 * 4 + 1]);
                acc[c4 * 4 + 2] = fmaf(a, b4.z, acc[c4 * 4 + 2]);
                acc[c4 * 4 + 3] = fmaf(a, b4.w, acc[c4 * 4 + 3]);
            }
        }
    }

    const float inv = 0.044194173824159216f;  // 1/sqrt(512)
    const int cq = t & 7, rr = t >> 3;
#pragma unroll
    for (int half = 0; half < 2; ++half) {
        __syncthreads();
#pragma unroll
        for (int ps = 0; ps < 8; ++ps) {
            int row = rr + ps * 32;
            float4 mv = *(const float4*)(mask + (size_t)(b * P_ + row) * N_ + col0 + half * 32 + cq * 4);
            Ls[row][cq * 4 + 0] = mv.x; Ls[row][cq * 4 + 1] = mv.y;
            Ls[row][cq * 4 + 2] = mv.z; Ls[row][cq * 4 + 3] = mv.w;
        }
        __syncthreads();
#pragma unroll
        for (int c = 0; c < 32; ++c)
            Ls[t][c] = 10.0f * tanhf(acc[half * 32 + c] * inv) + Ls[t][c];
        __syncthreads();
#pragma unroll
        for (int ps = 0; ps < 8; ++ps) {
            int row = rr + ps * 32;
            float4 o4 = make_float4(Ls[row][cq * 4 + 0], Ls[row][cq * 4 + 1],
                                    Ls[row][cq * 4 + 2], Ls[row][cq * 4 + 3]);
            *(float4*)(out + (size_t)(b * P_ + row) * N_ + col0 + half * 32 + cq * 4) = o4;
        }
    }
}

// ---------------------------------------------------------------------------
// K5: in-place row softmax (unchanged)
// ---------------------------------------------------------------------------
__global__ __launch_bounds__(256) void softmax_rows(float* __restrict__ io)
{
    const int t = threadIdx.x;
    float* r = io + (size_t)blockIdx.x * N_;
    float4 x = *(const float4*)(r + t * 4);
    float m = fmaxf(fmaxf(x.x, x.y), fmaxf(x.z, x.w));
#pragma unroll
    for (int off = 32; off > 0; off >>= 1) m = fmaxf(m, __shfl_xor(m, off));
    __shared__ float red[8];
    if ((t & 63) == 0) red[t >> 6] = m;
    __syncthreads();
    m = fmaxf(fmaxf(red[0], red[1]), fmaxf(red[2], red[3]));
    float e0 = __expf(x.x - m), e1 = __expf(x.y - m);
    float e2 = __expf(x.z - m), e3 = __expf(x.w - m);
    float s = (e0 + e1) + (e2 + e3);
#pragma unroll
    for (int off = 32; off > 0; off >>= 1) s += __shfl_xor(s, off);
    if ((t & 63) == 0) red[4 + (t >> 6)] = s;
    __syncthreads();
    s = (red[4] + red[5]) + (red[6] + red[7]);
    float inv = 1.0f / s;
    *(float4*)(r + t * 4) = make_float4(e0 * inv, e1 * inv, e2 * inv, e3 * inv);
}

extern "C" void kernel_launch(void* const* d_in, const int* in_sizes, int n_in,
                              void* d_out, int out_size, void* d_ws, size_t ws_size,
                              hipStream_t stream)
{
    (void)in_sizes; (void)n_in; (void)d_ws; (void)ws_size; (void)out_size;
    const float* x   = (const float*)d_in[0];
    const float* msk = (const float*)d_in[1];
    const float* qf  = (const float*)d_in[2];
    const float* kk  = (const float*)d_in[3];
    const float* vv  = (const float*)d_in[4];
    const float* shk = (const float*)d_in[5];
    const float* wq  = (const float*)d_in[6];
    const float* wc  = (const float*)d_in[7];
    float* out = (float*)d_out;

    gemm_abt<1><<<dim3(16, 32), 256, 0, stream>>>(x, wq, qf);
    attn_mfma<<<dim3(B_ * H_), 256, 0, stream>>>(kk, vv, msk);
    gemm_abt<0><<<dim3(16, 32), 256, 0, stream>>>(nullptr, wc, nullptr);
    gemm_ptr<<<dim3(16, 32), 256, 0, stream>>>(shk, msk, out);
    softmax_rows<<<dim3(B_ * P_), 256, 0, stream>>>(out);
}

// Round 3
// 796.708 us; speedup vs baseline: 2.3543x; 1.6501x over previous
//
#include <hip/hip_runtime.h>

#define B_ 32
#define P_ 256
#define N_ 1024
#define E_ 512
#define H_ 16
#define D_ 32

static_assert(E_ == H_ * D_, "");

typedef __attribute__((ext_vector_type(8))) short bf16x8;
typedef __attribute__((ext_vector_type(4))) float f32x4;

// Intermediates in static device memory (graph-capture safe).
__device__ float g_q[B_ * P_ * E_];    // (q_first + x@Wq^T) * rsqrt(32), [B,P,H*D]
__device__ float g_att[B_ * P_ * E_];  // attention out_concat, [B,P,E]
// Split bf16 planes (hi/lo): value ~= hi + lo, each exactly bf16.
__device__ __attribute__((aligned(16))) unsigned short g_mh_hi[B_ * P_ * E_];
__device__ __attribute__((aligned(16))) unsigned short g_mh_lo[B_ * P_ * E_];
__device__ __attribute__((aligned(16))) unsigned short g_wq_hi[E_ * E_];
__device__ __attribute__((aligned(16))) unsigned short g_wq_lo[E_ * E_];
__device__ __attribute__((aligned(16))) unsigned short g_wc_hi[E_ * E_];
__device__ __attribute__((aligned(16))) unsigned short g_wc_lo[E_ * E_];
__device__ __attribute__((aligned(16))) unsigned short g_shkT_hi[B_ * N_ * E_];  // [b][n][e]
__device__ __attribute__((aligned(16))) unsigned short g_shkT_lo[B_ * N_ * E_];

__device__ __forceinline__ unsigned short f2h(float x) {
    return (unsigned short)(__float_as_uint(x) >> 16);  // truncate to bf16
}
__device__ __forceinline__ float hi_f(float x) {
    return __uint_as_float(__float_as_uint(x) & 0xffff0000u);
}
__device__ __forceinline__ void split8(const float* xv, bf16x8& h, bf16x8& l) {
#pragma unroll
    for (int j = 0; j < 8; ++j) {
        float x = xv[j];
        h[j] = (short)f2h(x);
        l[j] = (short)f2h(x - hi_f(x));
    }
}

// ---------------------------------------------------------------------------
// P0a: split Wq and Wc into bf16 hi/lo planes (layout preserved, k-contig).
// ---------------------------------------------------------------------------
__global__ __launch_bounds__(256) void split_w_kernel(const float* __restrict__ wq,
                                                      const float* __restrict__ wc)
{
    int tid = blockIdx.x * 256 + threadIdx.x;  // 131072 threads, 4 elems each
    const float* src = (tid < 65536) ? wq : wc;
    unsigned short* dh = (tid < 65536) ? g_wq_hi : g_wc_hi;
    unsigned short* dl = (tid < 65536) ? g_wq_lo : g_wc_lo;
    int i = (tid & 65535) * 4;
    float4 v = *(const float4*)(src + i);
    ushort4 h = make_ushort4(f2h(v.x), f2h(v.y), f2h(v.z), f2h(v.w));
    ushort4 l = make_ushort4(f2h(v.x - hi_f(v.x)), f2h(v.y - hi_f(v.y)),
                             f2h(v.z - hi_f(v.z)), f2h(v.w - hi_f(v.w)));
    *(ushort4*)(dh + i) = h;
    *(ushort4*)(dl + i) = l;
}

// ---------------------------------------------------------------------------
// P0b: transpose+split single_head_key [b][e][n] -> planes [b][n][e].
// 64x64 tiles via LDS.
// ---------------------------------------------------------------------------
__global__ __launch_bounds__(256) void split_shkT_kernel(const float* __restrict__ shk)
{
    __shared__ float T[64][65];
    const int t = threadIdx.x;
    const int n0 = blockIdx.x * 64, e0 = blockIdx.y * 64, b = blockIdx.z;
    const float* src = shk + (size_t)b * E_ * N_;
    const int er = t >> 4, nq = t & 15;
#pragma unroll
    for (int ps = 0; ps < 4; ++ps) {
        int e = ps * 16 + er;
        float4 v = *(const float4*)(src + (size_t)(e0 + e) * N_ + n0 + nq * 4);
        T[nq * 4 + 0][e] = v.x; T[nq * 4 + 1][e] = v.y;
        T[nq * 4 + 2][e] = v.z; T[nq * 4 + 3][e] = v.w;
    }
    __syncthreads();
    const int nr = t >> 4, eq = t & 15;
    unsigned short* dh = g_shkT_hi + (size_t)b * N_ * E_;
    unsigned short* dl = g_shkT_lo + (size_t)b * N_ * E_;
#pragma unroll
    for (int ps = 0; ps < 4; ++ps) {
        int n = ps * 16 + nr;
        float v0 = T[n][eq * 4 + 0], v1 = T[n][eq * 4 + 1];
        float v2 = T[n][eq * 4 + 2], v3 = T[n][eq * 4 + 3];
        size_t o = (size_t)(n0 + n) * E_ + e0 + eq * 4;
        *(ushort4*)(dh + o) = make_ushort4(f2h(v0), f2h(v1), f2h(v2), f2h(v3));
        *(ushort4*)(dl + o) = make_ushort4(f2h(v0 - hi_f(v0)), f2h(v1 - hi_f(v1)),
                                           f2h(v2 - hi_f(v2)), f2h(v3 - hi_f(v3)));
    }
}

// ---------------------------------------------------------------------------
// K1 (MODE=1): g_q = (x @ Wq^T + qf) * rsqrt(32)      [fp32 out]
// K3 (MODE=0): g_mh planes = g_att @ Wc^T             [hi/lo bf16 out]
// Split-bf16 MFMA: S = AhBh + AlBh + AhBl. Block: 16 rows x 512 cols,
// 4 waves (each 16x128). A split in-kernel (read once); B = pre-split planes
// (L2-resident, direct bf16x8 loads, zero split VALU in K-loop).
// A-frag row=lane&15, k=8*(lane>>4)+j; B-frag col=lane&15, same k;
// D col=lane&15, row=4*(lane>>4)+r  (HW-validated in round 2).
// ---------------------------------------------------------------------------
template <int MODE>
__global__ __launch_bounds__(256) void mfma_ee(const float* __restrict__ Ain_,
                                               const float* __restrict__ qf)
{
    const int t = threadIdx.x, w = t >> 6, lane = t & 63;
    const int q16 = lane >> 4, c = lane & 15;
    const int row0 = blockIdx.x * 16;
    const int col0 = w * 128;
    const float* Ain = (MODE == 1) ? Ain_ : g_att;
    const unsigned short* Bh = (MODE == 1) ? g_wq_hi : g_wc_hi;
    const unsigned short* Bl = (MODE == 1) ? g_wq_lo : g_wc_lo;

    f32x4 acc[8];
#pragma unroll
    for (int nt = 0; nt < 8; ++nt) acc[nt] = (f32x4){0.f, 0.f, 0.f, 0.f};

#pragma unroll 1
    for (int kc = 0; kc < 512; kc += 32) {
        const float* ap = Ain + (size_t)(row0 + c) * 512 + kc + q16 * 8;
        float4 a0 = *(const float4*)ap;
        float4 a1 = *(const float4*)(ap + 4);
        float xv[8] = {a0.x, a0.y, a0.z, a0.w, a1.x, a1.y, a1.z, a1.w};
        bf16x8 ah, al;
        split8(xv, ah, al);
#pragma unroll
        for (int nt = 0; nt < 8; ++nt) {
            size_t bo = (size_t)(col0 + nt * 16 + c) * 512 + kc + q16 * 8;
            bf16x8 bh = *(const bf16x8*)(Bh + bo);
            bf16x8 bl = *(const bf16x8*)(Bl + bo);
            acc[nt] = __builtin_amdgcn_mfma_f32_16x16x32_bf16(ah, bh, acc[nt], 0, 0, 0);
            acc[nt] = __builtin_amdgcn_mfma_f32_16x16x32_bf16(al, bh, acc[nt], 0, 0, 0);
            acc[nt] = __builtin_amdgcn_mfma_f32_16x16x32_bf16(ah, bl, acc[nt], 0, 0, 0);
        }
    }

#pragma unroll
    for (int nt = 0; nt < 8; ++nt)
#pragma unroll
        for (int r = 0; r < 4; ++r) {
            int grow = row0 + 4 * q16 + r;
            int col = col0 + nt * 16 + c;
            float v = acc[nt][r];
            if (MODE == 1) {
                int bb = grow >> 8, p = grow & 255, h = col >> 5, d = col & 31;
                v = (v + qf[(((size_t)bb * 16 + h) * 256 + p) * 32 + d]) * 0.17677669529663687f;
                g_q[(size_t)grow * 512 + col] = v;
            } else {
                g_mh_hi[(size_t)grow * 512 + col] = f2h(v);
                g_mh_lo[(size_t)grow * 512 + col] = f2h(v - hi_f(v));
            }
        }
}

// ---------------------------------------------------------------------------
// K2: MFMA flash attention (unchanged from round 2 — validated).
// ---------------------------------------------------------------------------
__global__ __launch_bounds__(256, 2) void attn_mfma(const float* __restrict__ kg,
                                                    const float* __restrict__ vg,
                                                    const float* __restrict__ mask)
{
    __shared__ __align__(16) unsigned P_lds[4][64 * 36];
    const int t = threadIdx.x;
    const int w = t >> 6;
    const int lane = t & 63;
    const int q16 = lane >> 4;
    const int c = lane & 15;
    const int b = blockIdx.x >> 4;
    const int h = blockIdx.x & 15;
    const float* kb = kg + (size_t)(b * H_ + h) * N_ * D_;
    const float* vb = vg + (size_t)(b * H_ + h) * N_ * D_;
    const float* mb = mask + (size_t)b * P_ * N_ + (size_t)(w * 64) * N_;
    unsigned* Pw = P_lds[w];

    bf16x8 qh[4], ql[4];
#pragma unroll
    for (int pt = 0; pt < 4; ++pt) {
        const float* qrow = g_q + (size_t)(b * P_ + w * 64 + pt * 16 + c) * E_ + h * D_ + q16 * 8;
        float4 x0 = *(const float4*)qrow;
        float4 x1 = *(const float4*)(qrow + 4);
        float xv[8] = {x0.x, x0.y, x0.z, x0.w, x1.x, x1.y, x1.z, x1.w};
        split8(xv, qh[pt], ql[pt]);
    }

    f32x4 acc[4][2];
#pragma unroll
    for (int pt = 0; pt < 4; ++pt)
#pragma unroll
        for (int dt = 0; dt < 2; ++dt) acc[pt][dt] = (f32x4){0.f, 0.f, 0.f, 0.f};
    float lsum[4][4];
#pragma unroll
    for (int pt = 0; pt < 4; ++pt)
#pragma unroll
        for (int r = 0; r < 4; ++r) lsum[pt][r] = 0.f;

#pragma unroll 1
    for (int n0 = 0; n0 < N_; n0 += 32) {
        bf16x8 kh[2], kl[2];
#pragma unroll
        for (int nt = 0; nt < 2; ++nt) {
            const float* krow = kb + (size_t)(n0 + nt * 16 + c) * D_ + q16 * 8;
            float4 x0 = *(const float4*)krow;
            float4 x1 = *(const float4*)(krow + 4);
            float xv[8] = {x0.x, x0.y, x0.z, x0.w, x1.x, x1.y, x1.z, x1.w};
            split8(xv, kh[nt], kl[nt]);
        }
        bf16x8 vh[2], vl[2];
#pragma unroll
        for (int dt = 0; dt < 2; ++dt) {
            const float* vcol = vb + (size_t)(n0 + q16 * 8) * D_ + dt * 16 + c;
            float xv[8];
#pragma unroll
            for (int j = 0; j < 8; ++j) xv[j] = vcol[(size_t)j * D_];
            split8(xv, vh[dt], vl[dt]);
        }

#pragma unroll
        for (int pt = 0; pt < 4; ++pt) {
#pragma unroll
            for (int nt = 0; nt < 2; ++nt) {
                f32x4 s = (f32x4){0.f, 0.f, 0.f, 0.f};
                s = __builtin_amdgcn_mfma_f32_16x16x32_bf16(qh[pt], kh[nt], s, 0, 0, 0);
                s = __builtin_amdgcn_mfma_f32_16x16x32_bf16(ql[pt], kh[nt], s, 0, 0, 0);
                s = __builtin_amdgcn_mfma_f32_16x16x32_bf16(qh[pt], kl[nt], s, 0, 0, 0);
#pragma unroll
                for (int r = 0; r < 4; ++r) {
                    int prow = pt * 16 + 4 * q16 + r;
                    int ncol = n0 + nt * 16 + c;
                    float sc = s[r] + mb[(size_t)prow * N_ + ncol];
                    float pe = __expf(sc - 12.0f);
                    lsum[pt][r] += pe;
                    float peh = hi_f(pe);
                    unsigned pk = (__float_as_uint(pe) >> 16) |
                                  ((__float_as_uint(pe - peh) >> 16) << 16);
                    Pw[prow * 36 + nt * 16 + c] = pk;
                }
            }
        }

#pragma unroll
        for (int pt = 0; pt < 4; ++pt) {
            const unsigned* prd = &Pw[(pt * 16 + c) * 36 + q16 * 8];
            uint4 r0 = *(const uint4*)prd;
            uint4 r1 = *(const uint4*)(prd + 4);
            unsigned u[8] = {r0.x, r0.y, r0.z, r0.w, r1.x, r1.y, r1.z, r1.w};
            bf16x8 ph, plo;
#pragma unroll
            for (int j = 0; j < 8; ++j) {
                ph[j]  = (short)(u[j] & 0xffffu);
                plo[j] = (short)(u[j] >> 16);
            }
#pragma unroll
            for (int dt = 0; dt < 2; ++dt) {
                acc[pt][dt] = __builtin_amdgcn_mfma_f32_16x16x32_bf16(ph,  vh[dt], acc[pt][dt], 0, 0, 0);
                acc[pt][dt] = __builtin_amdgcn_mfma_f32_16x16x32_bf16(ph,  vl[dt], acc[pt][dt], 0, 0, 0);
                acc[pt][dt] = __builtin_amdgcn_mfma_f32_16x16x32_bf16(plo, vh[dt], acc[pt][dt], 0, 0, 0);
            }
        }
    }

#pragma unroll
    for (int pt = 0; pt < 4; ++pt)
#pragma unroll
        for (int r = 0; r < 4; ++r) {
            float v = lsum[pt][r];
            v += __shfl_xor(v, 1);
            v += __shfl_xor(v, 2);
            v += __shfl_xor(v, 4);
            v += __shfl_xor(v, 8);
            lsum[pt][r] = 1.0f / v;
        }

#pragma unroll
    for (int pt = 0; pt < 4; ++pt)
#pragma unroll
        for (int dt = 0; dt < 2; ++dt)
#pragma unroll
            for (int r = 0; r < 4; ++r) {
                int p = w * 64 + pt * 16 + 4 * q16 + r;
                g_att[(size_t)(b * P_ + p) * E_ + h * D_ + dt * 16 + c] =
                    acc[pt][dt][r] * lsum[pt][r];
            }
}

// ---------------------------------------------------------------------------
// K4: fused pointer GEMM + tanh-clip + masked softmax.
// probs[b,p,n] = softmax_n(10*tanh((g_mh[b] @ shkT[b]^T)/sqrt(E)) + mask)
// Block: 32 p x 1024 n (one batch slice), 8 waves = 2 p-groups x 4 n-groups,
// wave tile 16p x 256n (16 n-tiles, acc 64 f32). Both operands pre-split
// planes -> K-loop is pure direct loads + MFMA. Softmax with fixed max 10
// (logits bounded by tanh-clip; masked -> exp underflows to 0 exactly).
// Cross-wave n-reduction via tiny LDS.
// ---------------------------------------------------------------------------
__global__ __launch_bounds__(512) void ptr_fused(const float* __restrict__ mask,
                                                 float* __restrict__ out)
{
    __shared__ float red[2][16][4];
    const int t = threadIdx.x, w = t >> 6, lane = t & 63;
    const int q16 = lane >> 4, c = lane & 15;
    const int b = blockIdx.y;
    const int pg = w >> 2, ng = w & 3;
    const int p0 = blockIdx.x * 32 + pg * 16;
    const int n_base = ng * 256;
    const unsigned short* Ah = g_mh_hi + ((size_t)b * P_ + p0 + c) * E_;
    const unsigned short* Al = g_mh_lo + ((size_t)b * P_ + p0 + c) * E_;
    const unsigned short* Bh = g_shkT_hi + (size_t)b * N_ * E_;
    const unsigned short* Bl = g_shkT_lo + (size_t)b * N_ * E_;

    f32x4 acc[16];
#pragma unroll
    for (int nt = 0; nt < 16; ++nt) acc[nt] = (f32x4){0.f, 0.f, 0.f, 0.f};

#pragma unroll 1
    for (int kc = 0; kc < 512; kc += 32) {
        bf16x8 ah = *(const bf16x8*)(Ah + kc + q16 * 8);
        bf16x8 al = *(const bf16x8*)(Al + kc + q16 * 8);
#pragma unroll
        for (int nt = 0; nt < 16; ++nt) {
            size_t bo = (size_t)(n_base + nt * 16 + c) * E_ + kc + q16 * 8;
            bf16x8 bh = *(const bf16x8*)(Bh + bo);
            bf16x8 bl = *(const bf16x8*)(Bl + bo);
            acc[nt] = __builtin_amdgcn_mfma_f32_16x16x32_bf16(ah, bh, acc[nt], 0, 0, 0);
            acc[nt] = __builtin_amdgcn_mfma_f32_16x16x32_bf16(al, bh, acc[nt], 0, 0, 0);
            acc[nt] = __builtin_amdgcn_mfma_f32_16x16x32_bf16(ah, bl, acc[nt], 0, 0, 0);
        }
    }

    // epilogue: logits = 10*tanh(raw/sqrt(512)); e = exp(logit - 10 + mask)
    //         = exp(mask - 20*rcp(exp(raw*2/sqrt(512)) + 1))
    const float* mb = mask + (size_t)b * P_ * N_;
    float rsum[4] = {0.f, 0.f, 0.f, 0.f};
#pragma unroll
    for (int nt = 0; nt < 16; ++nt)
#pragma unroll
        for (int r = 0; r < 4; ++r) {
            int p = p0 + 4 * q16 + r;
            int n = n_base + nt * 16 + c;
            float raw = acc[nt][r];
            float ex2 = __expf(raw * 0.088388347648318447f);  // 2/sqrt(512)
            float rc = __builtin_amdgcn_rcpf(ex2 + 1.0f);
            float m = mb[(size_t)p * N_ + n];
            float ev = __expf(fmaf(-20.0f, rc, m));
            acc[nt][r] = ev;
            rsum[r] += ev;
        }
#pragma unroll
    for (int r = 0; r < 4; ++r) {
        float v = rsum[r];
        v += __shfl_xor(v, 1);
        v += __shfl_xor(v, 2);
        v += __shfl_xor(v, 4);
        v += __shfl_xor(v, 8);
        if (c == 0) red[pg][4 * q16 + r][ng] = v;
    }
    __syncthreads();
    float inv[4];
#pragma unroll
    for (int r = 0; r < 4; ++r) {
        int rr = 4 * q16 + r;
        inv[r] = 1.0f / ((red[pg][rr][0] + red[pg][rr][1]) +
                         (red[pg][rr][2] + red[pg][rr][3]));
    }
    float* ob = out + (size_t)b * P_ * N_;
#pragma unroll
    for (int nt = 0; nt < 16; ++nt)
#pragma unroll
        for (int r = 0; r < 4; ++r) {
            int p = p0 + 4 * q16 + r;
            int n = n_base + nt * 16 + c;
            ob[(size_t)p * N_ + n] = acc[nt][r] * inv[r];
        }
}

extern "C" void kernel_launch(void* const* d_in, const int* in_sizes, int n_in,
                              void* d_out, int out_size, void* d_ws, size_t ws_size,
                              hipStream_t stream)
{
    (void)in_sizes; (void)n_in; (void)d_ws; (void)ws_size; (void)out_size;
    const float* x   = (const float*)d_in[0];
    const float* msk = (const float*)d_in[1];
    const float* qf  = (const float*)d_in[2];
    const float* kk  = (const float*)d_in[3];
    const float* vv  = (const float*)d_in[4];
    const float* shk = (const float*)d_in[5];
    const float* wq  = (const float*)d_in[6];
    const float* wc  = (const float*)d_in[7];
    float* out = (float*)d_out;

    split_w_kernel<<<512, 256, 0, stream>>>(wq, wc);
    split_shkT_kernel<<<dim3(16, 8, 32), 256, 0, stream>>>(shk);
    mfma_ee<1><<<512, 256, 0, stream>>>(x, qf);              // g_q
    attn_mfma<<<dim3(B_ * H_), 256, 0, stream>>>(kk, vv, msk);  // g_att
    mfma_ee<0><<<512, 256, 0, stream>>>(nullptr, nullptr);   // g_mh planes
    ptr_fused<<<dim3(8, 32), 512, 0, stream>>>(msk, out);    // probs
}